// Round 22
// baseline (221.627 us; speedup 1.0000x reference)
//
#include <hip/hip_runtime.h>
#include <math.h>

typedef unsigned short u16;
typedef __bf16 bf16x8 __attribute__((ext_vector_type(8)));
typedef float f32x4 __attribute__((ext_vector_type(4)));
typedef unsigned short u16x8 __attribute__((ext_vector_type(8)));

#define SHIFT 2

static __device__ __forceinline__ f32x4 mfma16(bf16x8 a, bf16x8 b, f32x4 c) {
  return __builtin_amdgcn_mfma_f32_16x16x32_bf16(a, b, c, 0, 0, 0);
}
// native cast -> compiler emits v_cvt_pk_bf16_f32 (RNE), fusing adjacent pairs
static __device__ __forceinline__ u16 f2bf(float f) {
  return __builtin_bit_cast(u16, (__bf16)f);
}
static __device__ __forceinline__ float bf2f(u16 u) {
  unsigned v = (unsigned)u << 16;
  return __builtin_bit_cast(float, v);
}
static __device__ __forceinline__ void stage16(const u16* g, u16* lbase, int lane) {
#if __has_builtin(__builtin_amdgcn_global_load_lds)
  __builtin_amdgcn_global_load_lds(
      (const __attribute__((address_space(1))) unsigned int*)g,
      (__attribute__((address_space(3))) unsigned int*)lbase, 16, 0, 0);
#else
  *(u16x8*)(lbase + lane * 8) = *(const u16x8*)g;
#endif
}

// ---------------- workspace layout (bytes) ----------------
#define OFF_KVWT  ((size_t)0)                          // 384x192 bf16
#define OFF_PRWT  (OFF_KVWT + 384*192*2)               // 192x192
#define OFF_FC1WT (OFF_PRWT + 192*192*2)               // 768x192
#define OFF_FC2WT (OFF_FC1WT + 768*192*2)              // 192x768
#define OFF_SKW   (OFF_FC2WT + 192*768*2)              // 65536x192 bf16 (window order)
#define OFF_QW    (OFF_SKW + (size_t)65536*192*2)
#define OFF_KVB   (OFF_QW + (size_t)65536*192*2)       // 65536x384 bf16 (window order)
#define OFF_POX   (OFF_KVB + (size_t)65536*384*2)      // 65536x192 bf16 (WINDOW order)
#define OFF_YB    (OFF_POX + (size_t)65536*192*2)      // 65536x192 bf16 (natural)
#define OFF_RPBG  (OFF_YB + (size_t)65536*192*2)       // 6x64x64 bf16 gathered rpb

// ---------------- K0: weight transpose + f32->bf16 + rpb gather ----------------
__global__ __launch_bounds__(256) void k_prep(
    const float* __restrict__ kv_w, const float* __restrict__ proj_w,
    const float* __restrict__ fc1_w, const float* __restrict__ fc2_w,
    const float* __restrict__ rpb,
    u16* __restrict__ kvT, u16* __restrict__ prT,
    u16* __restrict__ f1T, u16* __restrict__ f2T, u16* __restrict__ rpbg) {
  int i = blockIdx.x * 256 + threadIdx.x;
  if (i < 192 * 384) kvT[(i % 384) * 192 + i / 384] = f2bf(kv_w[i]);
  if (i < 192 * 192) prT[(i % 192) * 192 + i / 192] = f2bf(proj_w[i]);
  if (i < 192 * 768) f1T[(i % 768) * 192 + i / 768] = f2bf(fc1_w[i]);
  if (i < 768 * 192) f2T[(i % 192) * 768 + i / 192] = f2bf(fc2_w[i]);
  if (i < 24576) {
    int h = i >> 12, rem = i & 4095, qr = rem >> 6, kc = rem & 63;
    int qs = qr >> 4, qh = (qr >> 2) & 3, qx = qr & 3;
    int ks = kc >> 4, kh = (kc >> 2) & 3, kx = kc & 3;
    int idx = (qs - ks + 3) * 11 + (qh - kh + 3) * 7 + (qx - kx + 3);
    rpbg[i] = f2bf(rpb[idx * 6 + h]);
  }
}

// ---------------- K1: LN + cyclic shift + window partition ----------------
__global__ __launch_bounds__(256) void k_ln_part(
    const float* __restrict__ skip, const float* __restrict__ x_up,
    const float* __restrict__ gam, const float* __restrict__ bet,
    u16* __restrict__ skw, u16* __restrict__ qw) {
  int row = blockIdx.x * 4 + (threadIdx.x >> 6);
  int lane = threadIdx.x & 63;
  const float* sp = skip + (size_t)row * 192;
  const float* qp = x_up + (size_t)row * 192;
  float sv[3], qv[3], ss = 0.f, qs = 0.f;
#pragma unroll
  for (int j = 0; j < 3; j++) {
    sv[j] = sp[lane + 64 * j]; qv[j] = qp[lane + 64 * j];
    ss += sv[j]; qs += qv[j];
  }
#pragma unroll
  for (int m = 1; m < 64; m <<= 1) { ss += __shfl_xor(ss, m, 64); qs += __shfl_xor(qs, m, 64); }
  float sm = ss * (1.f / 192.f), qm = qs * (1.f / 192.f);
  float s2 = 0.f, q2 = 0.f;
#pragma unroll
  for (int j = 0; j < 3; j++) { float d = sv[j] - sm; s2 += d * d; d = qv[j] - qm; q2 += d * d; }
#pragma unroll
  for (int m = 1; m < 64; m <<= 1) { s2 += __shfl_xor(s2, m, 64); q2 += __shfl_xor(q2, m, 64); }
  float sr = rsqrtf(s2 * (1.f / 192.f) + 1e-5f), qr = rsqrtf(q2 * (1.f / 192.f) + 1e-5f);
  int b = row >> 15, l = row & 32767;
  int s = l >> 10, h = (l >> 5) & 31, w = l & 31;
  int s_ = (s - SHIFT) & 31, h_ = (h - SHIFT) & 31, w_ = (w - SHIFT) & 31;
  int wIdx = ((s_ >> 2) * 8 + (h_ >> 2)) * 8 + (w_ >> 2);
  int n = ((s_ & 3) * 4 + (h_ & 3)) * 4 + (w_ & 3);
  size_t orow = ((size_t)(b * 512 + wIdx) * 64 + n) * 192;
  const float scale = 0.17677669529663687f;  // 32^-0.5
#pragma unroll
  for (int j = 0; j < 3; j++) {
    int cc = lane + 64 * j;
    float gg = gam[cc], bb = bet[cc];
    skw[orow + cc] = f2bf((sv[j] - sm) * sr * gg + bb);
    qw[orow + cc]  = f2bf(((qv[j] - qm) * qr * gg + bb) * scale);
  }
}

// ---------------- K2: kv GEMM (weights staged once, swizzled; frozen) ----------
__global__ __launch_bounds__(256, 2) void k_kv(
    const u16* __restrict__ A, const u16* __restrict__ BT,
    const float* __restrict__ bias, u16* __restrict__ outh) {
  __shared__ u16 lw[192 * 192];
  int mb = blockIdx.x, nb = blockIdx.y;
  int tid = threadIdx.x, l = tid & 63, wv = tid >> 6, g = l >> 4, c = l & 15;
  int wr = wv >> 1, wc = wv & 1;
#pragma unroll
  for (int i = 0; i < 18; i++) {
    int CI = i * 256 + tid;
    int row = CI / 24, ch = CI % 24;
    int sch = (ch & 24) | ((ch ^ row) & 7);
    stage16(BT + (size_t)(nb * 192 + row) * 192 + sch * 8, lw + (i * 256 + wv * 64) * 8, l);
  }
  __syncthreads();
  f32x4 acc[4][6] = {};
#pragma unroll
  for (int ks = 0; ks < 6; ks++) {
    bf16x8 a[4];
#pragma unroll
    for (int m = 0; m < 4; m++)
      a[m] = *(const bf16x8*)&A[(size_t)(mb * 128 + wr * 64 + m * 16 + c) * 192 + ks * 32 + g * 8];
#pragma unroll
    for (int n = 0; n < 6; n++) {
      int col = wc * 96 + n * 16 + c;
      int ch = ks * 4 + g;
      int chp = (ch & 24) | ((ch ^ col) & 7);
      bf16x8 b = *(const bf16x8*)&lw[col * 192 + chp * 8];
#pragma unroll
      for (int m = 0; m < 4; m++) acc[m][n] = mfma16(a[m], b, acc[m][n]);
    }
  }
#pragma unroll
  for (int n = 0; n < 6; n++)
#pragma unroll
    for (int m = 0; m < 4; m++) {
      int col = nb * 192 + wc * 96 + n * 16 + c;
      float bb = bias[col];
#pragma unroll
      for (int r = 0; r < 4; r++) {
        int row = mb * 128 + wr * 64 + m * 16 + g * 4 + r;
        outh[(size_t)row * 384 + col] = f2bf(acc[m][n][r] + bb);
      }
    }
}

// ---------------- K3: attention + proj, swapped QK^T (frozen from r21) ---------
__global__ __launch_bounds__(384) void k_attn_mega(
    const u16* __restrict__ qw, const u16* __restrict__ kvb,
    const u16* __restrict__ rpbg, const float* __restrict__ mask,
    const u16* __restrict__ prT, const float* __restrict__ proj_b,
    u16* __restrict__ pox) {
  __shared__ __align__(16) char smem[38400];
  u16* lv = (u16*)smem;              // [64][192] V tile (stage16, linear)
  u16* lo = (u16*)smem;              // [64][200], aliases lv + head of lp
  u16* lp = (u16*)(smem + 24576);    // [6][16*72] per-head P slice
  int b_ = blockIdx.x, wIdx = b_ & 511;
  int tid = threadIdx.x, l = tid & 63, wv = tid >> 6, g = l >> 4, c = l & 15;
  int h = wv;
#pragma unroll
  for (int i = 0; i < 4; i++) {
    int CI = i * 384 + tid;
    int row = CI / 24, ch = CI % 24;
    stage16(kvb + ((size_t)b_ * 64 + row) * 384 + 192 + ch * 8,
            lv + (i * 384 + wv * 64) * 8, l);
  }
  const float* mrow = mask + (size_t)wIdx * 4096;
  float4 mv[4][4];  // [n(q-tile)][m(k-tile)]
#pragma unroll
  for (int n = 0; n < 4; n++)
#pragma unroll
    for (int m = 0; m < 4; m++)
      mv[n][m] = *(const float4*)&mrow[(n * 16 + c) * 64 + m * 16 + g * 4];
  bf16x8 qa[4], kb[4];
#pragma unroll
  for (int m = 0; m < 4; m++)
    qa[m] = *(const bf16x8*)&qw[((size_t)b_ * 64 + m * 16 + c) * 192 + h * 32 + g * 8];
#pragma unroll
  for (int n = 0; n < 4; n++)
    kb[n] = *(const bf16x8*)&kvb[((size_t)b_ * 64 + n * 16 + c) * 384 + h * 32 + g * 8];
  // hoist proj weight fragments early (ride under softmax/PV)
  bf16x8 pb[6][2];
#pragma unroll
  for (int ks = 0; ks < 6; ks++)
#pragma unroll
    for (int n = 0; n < 2; n++)
      pb[ks][n] = *(const bf16x8*)&prT[(size_t)(wv * 32 + n * 16 + c) * 192 + ks * 32 + g * 8];
  __syncthreads();  // stage16 drained
  bf16x8 vb[2][2];
#pragma unroll
  for (int kk = 0; kk < 2; kk++)
#pragma unroll
    for (int nd = 0; nd < 2; nd++) {
      union { u16 u[8]; bf16x8 v; } bb;
#pragma unroll
      for (int j = 0; j < 8; j++)
        bb.u[j] = lv[(kk * 32 + g * 8 + j) * 192 + h * 32 + nd * 16 + c];
      vb[kk][nd] = bb.v;
    }
  __syncthreads();  // lv dead
  f32x4 acc[4][4] = {};
  __builtin_amdgcn_s_setprio(1);
#pragma unroll
  for (int m = 0; m < 4; m++)
#pragma unroll
    for (int n = 0; n < 4; n++) acc[m][n] = mfma16(kb[m], qa[n], acc[m][n]);
  __builtin_amdgcn_s_setprio(0);
  const u16* rg = rpbg + h * 4096;
  f32x4 oacc[4][2] = {};
#pragma unroll
  for (int n = 0; n < 4; n++) {
    ushort4 rv[4];
#pragma unroll
    for (int m = 0; m < 4; m++)
      rv[m] = *(const ushort4*)&rg[(n * 16 + c) * 64 + m * 16 + g * 4];
    float vals[4][4];
    float mx = -3.4e38f;
#pragma unroll
    for (int m = 0; m < 4; m++) {
      float mr[4] = {mv[n][m].x, mv[n][m].y, mv[n][m].z, mv[n][m].w};
      u16 ru[4] = {rv[m].x, rv[m].y, rv[m].z, rv[m].w};
#pragma unroll
      for (int r = 0; r < 4; r++) {
        vals[m][r] = acc[m][n][r] + bf2f(ru[r]) + mr[r];
        mx = fmaxf(mx, vals[m][r]);
      }
    }
    mx = fmaxf(mx, __shfl_xor(mx, 16, 64));
    mx = fmaxf(mx, __shfl_xor(mx, 32, 64));
    float sum = 0.f;
#pragma unroll
    for (int m = 0; m < 4; m++)
#pragma unroll
      for (int r = 0; r < 4; r++) { vals[m][r] = __expf(vals[m][r] - mx); sum += vals[m][r]; }
    sum += __shfl_xor(sum, 16, 64);
    sum += __shfl_xor(sum, 32, 64);
    float inv = 1.f / sum;
#pragma unroll
    for (int m = 0; m < 4; m++) {
      unsigned p0 = f2bf(vals[m][0] * inv) | ((unsigned)f2bf(vals[m][1] * inv) << 16);
      unsigned p1 = f2bf(vals[m][2] * inv) | ((unsigned)f2bf(vals[m][3] * inv) << 16);
      *(uint2*)&lp[h * 1152 + c * 72 + m * 16 + g * 4] = make_uint2(p0, p1);
    }
    __builtin_amdgcn_s_setprio(1);
#pragma unroll
    for (int kk = 0; kk < 2; kk++) {
      bf16x8 pa = *(const bf16x8*)&lp[h * 1152 + c * 72 + kk * 32 + g * 8];
#pragma unroll
      for (int nd = 0; nd < 2; nd++) oacc[n][nd] = mfma16(pa, vb[kk][nd], oacc[n][nd]);
    }
    __builtin_amdgcn_s_setprio(0);
  }
  __syncthreads();  // all PV done -> lp dead -> lo writable
#pragma unroll
  for (int m = 0; m < 4; m++)
#pragma unroll
    for (int nd = 0; nd < 2; nd++)
#pragma unroll
      for (int r = 0; r < 4; r++)
        lo[(m * 16 + g * 4 + r) * 200 + h * 32 + nd * 16 + c] = f2bf(oacc[m][nd][r]);
  __syncthreads();
  f32x4 pacc[4][2] = {};
  __builtin_amdgcn_s_setprio(1);
#pragma unroll
  for (int ks = 0; ks < 6; ks++) {
    bf16x8 pa[4];
#pragma unroll
    for (int m = 0; m < 4; m++)
      pa[m] = *(const bf16x8*)&lo[(m * 16 + c) * 200 + ks * 32 + g * 8];
#pragma unroll
    for (int n = 0; n < 2; n++)
#pragma unroll
      for (int m = 0; m < 4; m++) pacc[m][n] = mfma16(pa[m], pb[ks][n], pacc[m][n]);
  }
  __builtin_amdgcn_s_setprio(0);
#pragma unroll
  for (int m = 0; m < 4; m++)
#pragma unroll
    for (int r = 0; r < 4; r++) {
      int tok = m * 16 + g * 4 + r;
#pragma unroll
      for (int n = 0; n < 2; n++) {
        int col = wv * 32 + n * 16 + c;
        pox[((size_t)b_ * 64 + tok) * 192 + col] = f2bf(pacc[m][n][r] + proj_b[col]);
      }
    }
}

// ---------------- K4: fused LN2 + MLP (r17 structure; VALU-shaved) -------------
// Deltas vs r21: hoisted staging offsets (o1/o2), hoisted LDS fragment offsets
// (chp8/chp2/abase), exp2-folded gelu. No layout/sync changes.
__global__ __launch_bounds__(512) void k_mlp(
    const float* __restrict__ x, const u16* __restrict__ pox,
    const float* __restrict__ g2, const float* __restrict__ b2,
    const u16* __restrict__ f1T, const u16* __restrict__ f2T,
    const float* __restrict__ b1, const float* __restrict__ b2f,
    u16* __restrict__ yb, float* __restrict__ out) {
  __shared__ u16 lds[33792];          // f1c 12288 | f2c 12288 | h1c 8x1152
  u16* f1c = lds;
  u16* f2c = lds + 12288;
  u16* h1c = lds + 24576;
  int tid = threadIdx.x, l = tid & 63, wv = tid >> 6, g = l >> 4, c = l & 15;
  size_t tok0 = (size_t)blockIdx.x * 128 + wv * 16;
  u16* tile = h1c + wv * 1152;        // wave-private [16][72]
  // hoisted staging source offsets (loop-invariant)
  int o1[3], o2[3];
#pragma unroll
  for (int i = 0; i < 3; i++) {
    int CI = i * 512 + tid;
    int r1 = CI / 24, c1 = CI % 24;
    o1[i] = r1 * 192 + ((c1 & 24) | ((c1 ^ r1) & 7)) * 8;
    int r2 = CI >> 3, c2 = CI & 7;
    o2[i] = r2 * 768 + (c2 ^ (r2 & 7)) * 8;
  }
  // hoisted LDS fragment offsets (ko-invariant)
  int chp8[6], abase[4], chp2[2];
#pragma unroll
  for (int ks = 0; ks < 6; ks++) {
    int ch = ks * 4 + g;
    chp8[ks] = ((ch & 24) | ((ch ^ c) & 7)) * 8;
  }
#pragma unroll
  for (int cf = 0; cf < 4; cf++) abase[cf] = (cf * 16 + c) * 192;
#pragma unroll
  for (int ck = 0; ck < 2; ck++) {
    int ch = ck * 4 + g;
    chp2[ck] = (ch ^ (c & 7)) * 8;
  }
  // prologue: issue chunk-0 weight stages first (latency overlaps LN)
#pragma unroll
  for (int i = 0; i < 3; i++)
    stage16(f1T + o1[i], f1c + (i * 512 + wv * 64) * 8, l);
#pragma unroll
  for (int i = 0; i < 3; i++)
    stage16(f2T + o2[i], f2c + (i * 512 + wv * 64) * 8, l);
  // LN2 for token t = tok0 + c
  int t = (int)tok0 + c;
  int bI = t >> 15, llt = t & 32767;
  int s = llt >> 10, hh = (llt >> 5) & 31, w = llt & 31;
  int s_ = (s - SHIFT) & 31, h_ = (hh - SHIFT) & 31, w_ = (w - SHIFT) & 31;
  int wI = ((s_ >> 2) * 8 + (h_ >> 2)) * 8 + (w_ >> 2);
  int nn = ((s_ & 3) * 4 + (h_ & 3)) * 4 + (w_ & 3);
  size_t wrow = ((size_t)(bI * 512 + wI) * 64 + nn) * 192;
  bf16x8 hb[6];
  float ss = 0.f, sq = 0.f;
#pragma unroll
  for (int ks = 0; ks < 6; ks++) {
    int ch0 = ks * 32 + g * 8;
    union { u16x8 p; u16 u[8]; } pk;
    pk.p = *(const u16x8*)&pox[wrow + ch0];
    float4 xa = *(const float4*)&x[(size_t)t * 192 + ch0];
    float4 xb = *(const float4*)&x[(size_t)t * 192 + ch0 + 4];
    float y[8] = {xa.x, xa.y, xa.z, xa.w, xb.x, xb.y, xb.z, xb.w};
    union { u16 u[8]; u16x8 v; bf16x8 bv; } yy;
#pragma unroll
    for (int j = 0; j < 8; j++) {
      y[j] += bf2f(pk.u[j]);
      ss += y[j]; sq += y[j] * y[j];
      yy.u[j] = f2bf(y[j]);
    }
    *(u16x8*)&yb[(size_t)t * 192 + ch0] = yy.v;
    hb[ks] = yy.bv;
  }
  ss += __shfl_xor(ss, 16, 64); ss += __shfl_xor(ss, 32, 64);
  sq += __shfl_xor(sq, 16, 64); sq += __shfl_xor(sq, 32, 64);
  {
    float mu = ss * (1.f / 192.f);
    float rs = rsqrtf(sq * (1.f / 192.f) - mu * mu + 1e-5f);
#pragma unroll
    for (int ks = 0; ks < 6; ks++) {
      int ch0 = ks * 32 + g * 8;
      float4 ga = *(const float4*)&g2[ch0];
      float4 gb = *(const float4*)&g2[ch0 + 4];
      float4 ba = *(const float4*)&b2[ch0];
      float4 bb = *(const float4*)&b2[ch0 + 4];
      float gv[8] = {ga.x, ga.y, ga.z, ga.w, gb.x, gb.y, gb.z, gb.w};
      float bv[8] = {ba.x, ba.y, ba.z, ba.w, bb.x, bb.y, bb.z, bb.w};
      union { u16x8 v; u16 u[8]; bf16x8 bvv; } yy, hn_;
      yy.bvv = hb[ks];
#pragma unroll
      for (int j = 0; j < 8; j++)
        hn_.u[j] = f2bf((bf2f(yy.u[j]) - mu) * rs * gv[j] + bv[j]);
      hb[ks] = hn_.bvv;
    }
  }
  __syncthreads();  // chunk-0 stages drained
  f32x4 acc2[12] = {};
#pragma unroll 1
  for (int ko = 0; ko < 12; ko++) {
    // ---- fc1 (transposed): D1[h1col][tok] for this wave's 16 tokens ----
    f32x4 acc1[4] = {};
#pragma unroll
    for (int ks = 0; ks < 6; ks++) {
#pragma unroll
      for (int cf = 0; cf < 4; cf++) {
        bf16x8 wa = *(const bf16x8*)&f1c[abase[cf] + chp8[ks]];
        acc1[cf] = mfma16(wa, hb[ks], acc1[cf]);
      }
    }
    // ---- gelu (exp2-folded) -> wave-private tile ----
#pragma unroll
    for (int cf = 0; cf < 4; cf++) {
      float4 b1v = *(const float4*)&b1[ko * 64 + cf * 16 + g * 4];
      unsigned pk[2];
#pragma unroll
      for (int p = 0; p < 2; p++) {
        unsigned lohi[2];
#pragma unroll
        for (int q = 0; q < 2; q++) {
          int r = p * 2 + q;
          float v = acc1[cf][r] + (r == 0 ? b1v.x : r == 1 ? b1v.y : r == 2 ? b1v.z : b1v.w);
          float u2 = v * (2.3022652f + 0.10295394f * v * v);
          v = v * (1.f / (1.f + exp2f(-u2)));
          lohi[q] = f2bf(v);
        }
        pk[p] = lohi[0] | (lohi[1] << 16);
      }
      *(uint2*)&tile[c * 72 + cf * 16 + g * 4] = make_uint2(pk[0], pk[1]);
    }
    __syncthreads();  // all waves done reading f1c(ko); drains f2c(ko) stage
    if (ko < 11) {
      const u16* src = f1T + (size_t)(ko + 1) * 12288;
#pragma unroll
      for (int i = 0; i < 3; i++)
        stage16(src + o1[i], f1c + (i * 512 + wv * 64) * 8, l);
    }
    // ---- fc2 partial ----
#pragma unroll
    for (int ck = 0; ck < 2; ck++) {
      bf16x8 a2 = *(const bf16x8*)&tile[c * 72 + ck * 32 + g * 8];
#pragma unroll
      for (int of = 0; of < 12; of++) {
        bf16x8 wb = *(const bf16x8*)&f2c[(of * 16 + c) * 64 + chp2[ck]];
        acc2[of] = mfma16(a2, wb, acc2[of]);
      }
    }
    __syncthreads();  // all waves done reading f2c(ko); drains f1c(ko+1) stage
    if (ko < 11) {
      const u16* src = f2T + (size_t)(ko + 1) * 64;
#pragma unroll
      for (int i = 0; i < 3; i++)
        stage16(src + o2[i], f2c + (i * 512 + wv * 64) * 8, l);
    }
  }
  // ---- epilogue: out = fc2 + bias + y (yb bf16, L2/L3-hot) ----
#pragma unroll
  for (int of = 0; of < 12; of++) {
    int col = of * 16 + c;
    float bb = b2f[col];
#pragma unroll
    for (int r = 0; r < 4; r++) {
      size_t trow = tok0 + g * 4 + r;
      size_t base = trow * 192 + col;
      out[base] = acc2[of][r] + bb + bf2f(yb[base]);
    }
  }
}

extern "C" void kernel_launch(void* const* d_in, const int* in_sizes, int n_in,
                              void* d_out, int out_size, void* d_ws, size_t ws_size,
                              hipStream_t stream) {
  const float* x      = (const float*)d_in[0];
  const float* mask   = (const float*)d_in[1];
  const float* skip   = (const float*)d_in[2];
  const float* x_up   = (const float*)d_in[3];
  const float* n1g    = (const float*)d_in[4];
  const float* n1b    = (const float*)d_in[5];
  const float* kv_w   = (const float*)d_in[6];
  const float* kv_b   = (const float*)d_in[7];
  const float* rpb    = (const float*)d_in[8];
  const float* proj_w = (const float*)d_in[9];
  const float* proj_b = (const float*)d_in[10];
  const float* n2g    = (const float*)d_in[11];
  const float* n2b    = (const float*)d_in[12];
  const float* fc1_w  = (const float*)d_in[13];
  const float* fc1_b  = (const float*)d_in[14];
  const float* fc2_w  = (const float*)d_in[15];
  const float* fc2_b  = (const float*)d_in[16];
  char* ws = (char*)d_ws;
  u16* kvT  = (u16*)(ws + OFF_KVWT);
  u16* prT  = (u16*)(ws + OFF_PRWT);
  u16* f1T  = (u16*)(ws + OFF_FC1WT);
  u16* f2T  = (u16*)(ws + OFF_FC2WT);
  u16* skw  = (u16*)(ws + OFF_SKW);
  u16* qw   = (u16*)(ws + OFF_QW);
  u16* kvb  = (u16*)(ws + OFF_KVB);
  u16* pox  = (u16*)(ws + OFF_POX);
  u16* yb   = (u16*)(ws + OFF_YB);
  u16* rpbg = (u16*)(ws + OFF_RPBG);
  float* out = (float*)d_out;

  k_prep<<<dim3(576), dim3(256), 0, stream>>>(kv_w, proj_w, fc1_w, fc2_w, rpb,
                                              kvT, prT, f1T, f2T, rpbg);
  k_ln_part<<<dim3(16384), dim3(256), 0, stream>>>(skip, x_up, n1g, n1b, skw, qw);
  k_kv<<<dim3(512, 2), dim3(256), 0, stream>>>(skw, kvT, kv_b, kvb);
  k_attn_mega<<<dim3(1024), dim3(384), 0, stream>>>(
      qw, kvb, rpbg, mask, prT, proj_b, pox);
  k_mlp<<<dim3(512), dim3(512), 0, stream>>>(
      x, pox, n2g, n2b, f1T, f2T, fc1_b, fc2_b, yb, out);
}

// Round 23
// 216.749 us; speedup vs baseline: 1.0225x; 1.0225x over previous
//
#include <hip/hip_runtime.h>
#include <math.h>

typedef unsigned short u16;
typedef __bf16 bf16x8 __attribute__((ext_vector_type(8)));
typedef float f32x4 __attribute__((ext_vector_type(4)));
typedef unsigned short u16x8 __attribute__((ext_vector_type(8)));

#define SHIFT 2

static __device__ __forceinline__ f32x4 mfma16(bf16x8 a, bf16x8 b, f32x4 c) {
  return __builtin_amdgcn_mfma_f32_16x16x32_bf16(a, b, c, 0, 0, 0);
}
// native cast -> compiler emits v_cvt_pk_bf16_f32 (RNE), fusing adjacent pairs
static __device__ __forceinline__ u16 f2bf(float f) {
  return __builtin_bit_cast(u16, (__bf16)f);
}
static __device__ __forceinline__ float bf2f(u16 u) {
  unsigned v = (unsigned)u << 16;
  return __builtin_bit_cast(float, v);
}
static __device__ __forceinline__ void stage16(const u16* g, u16* lbase, int lane) {
#if __has_builtin(__builtin_amdgcn_global_load_lds)
  __builtin_amdgcn_global_load_lds(
      (const __attribute__((address_space(1))) unsigned int*)g,
      (__attribute__((address_space(3))) unsigned int*)lbase, 16, 0, 0);
#else
  *(u16x8*)(lbase + lane * 8) = *(const u16x8*)g;
#endif
}

// ---------------- workspace layout (bytes) ----------------
#define OFF_KVWT  ((size_t)0)                          // 384x192 bf16
#define OFF_PRWT  (OFF_KVWT + 384*192*2)               // 192x192
#define OFF_FC1WT (OFF_PRWT + 192*192*2)               // 768x192
#define OFF_FC2WT (OFF_FC1WT + 768*192*2)              // 192x768
#define OFF_SKW   (OFF_FC2WT + 192*768*2)              // 65536x192 bf16 (window order)
#define OFF_QW    (OFF_SKW + (size_t)65536*192*2)
#define OFF_KVB   (OFF_QW + (size_t)65536*192*2)       // 65536x384 bf16 (window order)
#define OFF_POX   (OFF_KVB + (size_t)65536*384*2)      // 65536x192 bf16 (WINDOW order)
#define OFF_YB    (OFF_POX + (size_t)65536*192*2)      // 65536x192 bf16 (natural)
#define OFF_RPBG  (OFF_YB + (size_t)65536*192*2)       // 6x64x64 bf16 gathered rpb

// ---------------- K0: weight transpose + f32->bf16 + rpb gather ----------------
__global__ __launch_bounds__(256) void k_prep(
    const float* __restrict__ kv_w, const float* __restrict__ proj_w,
    const float* __restrict__ fc1_w, const float* __restrict__ fc2_w,
    const float* __restrict__ rpb,
    u16* __restrict__ kvT, u16* __restrict__ prT,
    u16* __restrict__ f1T, u16* __restrict__ f2T, u16* __restrict__ rpbg) {
  int i = blockIdx.x * 256 + threadIdx.x;
  if (i < 192 * 384) kvT[(i % 384) * 192 + i / 384] = f2bf(kv_w[i]);
  if (i < 192 * 192) prT[(i % 192) * 192 + i / 192] = f2bf(proj_w[i]);
  if (i < 192 * 768) f1T[(i % 768) * 192 + i / 768] = f2bf(fc1_w[i]);
  if (i < 768 * 192) f2T[(i % 192) * 768 + i / 192] = f2bf(fc2_w[i]);
  if (i < 24576) {
    int h = i >> 12, rem = i & 4095, qr = rem >> 6, kc = rem & 63;
    int qs = qr >> 4, qh = (qr >> 2) & 3, qx = qr & 3;
    int ks = kc >> 4, kh = (kc >> 2) & 3, kx = kc & 3;
    int idx = (qs - ks + 3) * 11 + (qh - kh + 3) * 7 + (qx - kx + 3);
    rpbg[i] = f2bf(rpb[idx * 6 + h]);
  }
}

// ---------------- K1: LN + cyclic shift + window partition ----------------
__global__ __launch_bounds__(256) void k_ln_part(
    const float* __restrict__ skip, const float* __restrict__ x_up,
    const float* __restrict__ gam, const float* __restrict__ bet,
    u16* __restrict__ skw, u16* __restrict__ qw) {
  int row = blockIdx.x * 4 + (threadIdx.x >> 6);
  int lane = threadIdx.x & 63;
  const float* sp = skip + (size_t)row * 192;
  const float* qp = x_up + (size_t)row * 192;
  float sv[3], qv[3], ss = 0.f, qs = 0.f;
#pragma unroll
  for (int j = 0; j < 3; j++) {
    sv[j] = sp[lane + 64 * j]; qv[j] = qp[lane + 64 * j];
    ss += sv[j]; qs += qv[j];
  }
#pragma unroll
  for (int m = 1; m < 64; m <<= 1) { ss += __shfl_xor(ss, m, 64); qs += __shfl_xor(qs, m, 64); }
  float sm = ss * (1.f / 192.f), qm = qs * (1.f / 192.f);
  float s2 = 0.f, q2 = 0.f;
#pragma unroll
  for (int j = 0; j < 3; j++) { float d = sv[j] - sm; s2 += d * d; d = qv[j] - qm; q2 += d * d; }
#pragma unroll
  for (int m = 1; m < 64; m <<= 1) { s2 += __shfl_xor(s2, m, 64); q2 += __shfl_xor(q2, m, 64); }
  float sr = rsqrtf(s2 * (1.f / 192.f) + 1e-5f), qr = rsqrtf(q2 * (1.f / 192.f) + 1e-5f);
  int b = row >> 15, l = row & 32767;
  int s = l >> 10, h = (l >> 5) & 31, w = l & 31;
  int s_ = (s - SHIFT) & 31, h_ = (h - SHIFT) & 31, w_ = (w - SHIFT) & 31;
  int wIdx = ((s_ >> 2) * 8 + (h_ >> 2)) * 8 + (w_ >> 2);
  int n = ((s_ & 3) * 4 + (h_ & 3)) * 4 + (w_ & 3);
  size_t orow = ((size_t)(b * 512 + wIdx) * 64 + n) * 192;
  const float scale = 0.17677669529663687f;  // 32^-0.5
#pragma unroll
  for (int j = 0; j < 3; j++) {
    int cc = lane + 64 * j;
    float gg = gam[cc], bb = bet[cc];
    skw[orow + cc] = f2bf((sv[j] - sm) * sr * gg + bb);
    qw[orow + cc]  = f2bf(((qv[j] - qm) * qr * gg + bb) * scale);
  }
}

// ---------------- K2: kv GEMM (weights staged once, swizzled; frozen) ----------
__global__ __launch_bounds__(256, 2) void k_kv(
    const u16* __restrict__ A, const u16* __restrict__ BT,
    const float* __restrict__ bias, u16* __restrict__ outh) {
  __shared__ u16 lw[192 * 192];
  int mb = blockIdx.x, nb = blockIdx.y;
  int tid = threadIdx.x, l = tid & 63, wv = tid >> 6, g = l >> 4, c = l & 15;
  int wr = wv >> 1, wc = wv & 1;
#pragma unroll
  for (int i = 0; i < 18; i++) {
    int CI = i * 256 + tid;
    int row = CI / 24, ch = CI % 24;
    int sch = (ch & 24) | ((ch ^ row) & 7);
    stage16(BT + (size_t)(nb * 192 + row) * 192 + sch * 8, lw + (i * 256 + wv * 64) * 8, l);
  }
  __syncthreads();
  f32x4 acc[4][6] = {};
#pragma unroll
  for (int ks = 0; ks < 6; ks++) {
    bf16x8 a[4];
#pragma unroll
    for (int m = 0; m < 4; m++)
      a[m] = *(const bf16x8*)&A[(size_t)(mb * 128 + wr * 64 + m * 16 + c) * 192 + ks * 32 + g * 8];
#pragma unroll
    for (int n = 0; n < 6; n++) {
      int col = wc * 96 + n * 16 + c;
      int ch = ks * 4 + g;
      int chp = (ch & 24) | ((ch ^ col) & 7);
      bf16x8 b = *(const bf16x8*)&lw[col * 192 + chp * 8];
#pragma unroll
      for (int m = 0; m < 4; m++) acc[m][n] = mfma16(a[m], b, acc[m][n]);
    }
  }
#pragma unroll
  for (int n = 0; n < 6; n++)
#pragma unroll
    for (int m = 0; m < 4; m++) {
      int col = nb * 192 + wc * 96 + n * 16 + c;
      float bb = bias[col];
#pragma unroll
      for (int r = 0; r < 4; r++) {
        int row = mb * 128 + wr * 64 + m * 16 + g * 4 + r;
        outh[(size_t)row * 384 + col] = f2bf(acc[m][n][r] + bb);
      }
    }
}

// ---------------- K3: attention + proj, swapped QK^T (frozen from r21) ---------
__global__ __launch_bounds__(384) void k_attn_mega(
    const u16* __restrict__ qw, const u16* __restrict__ kvb,
    const u16* __restrict__ rpbg, const float* __restrict__ mask,
    const u16* __restrict__ prT, const float* __restrict__ proj_b,
    u16* __restrict__ pox) {
  __shared__ __align__(16) char smem[38400];
  u16* lv = (u16*)smem;              // [64][192] V tile (stage16, linear)
  u16* lo = (u16*)smem;              // [64][200], aliases lv + head of lp
  u16* lp = (u16*)(smem + 24576);    // [6][16*72] per-head P slice
  int b_ = blockIdx.x, wIdx = b_ & 511;
  int tid = threadIdx.x, l = tid & 63, wv = tid >> 6, g = l >> 4, c = l & 15;
  int h = wv;
#pragma unroll
  for (int i = 0; i < 4; i++) {
    int CI = i * 384 + tid;
    int row = CI / 24, ch = CI % 24;
    stage16(kvb + ((size_t)b_ * 64 + row) * 384 + 192 + ch * 8,
            lv + (i * 384 + wv * 64) * 8, l);
  }
  const float* mrow = mask + (size_t)wIdx * 4096;
  float4 mv[4][4];  // [n(q-tile)][m(k-tile)]
#pragma unroll
  for (int n = 0; n < 4; n++)
#pragma unroll
    for (int m = 0; m < 4; m++)
      mv[n][m] = *(const float4*)&mrow[(n * 16 + c) * 64 + m * 16 + g * 4];
  bf16x8 qa[4], kb[4];
#pragma unroll
  for (int m = 0; m < 4; m++)
    qa[m] = *(const bf16x8*)&qw[((size_t)b_ * 64 + m * 16 + c) * 192 + h * 32 + g * 8];
#pragma unroll
  for (int n = 0; n < 4; n++)
    kb[n] = *(const bf16x8*)&kvb[((size_t)b_ * 64 + n * 16 + c) * 384 + h * 32 + g * 8];
  // hoist proj weight fragments early (ride under softmax/PV)
  bf16x8 pb[6][2];
#pragma unroll
  for (int ks = 0; ks < 6; ks++)
#pragma unroll
    for (int n = 0; n < 2; n++)
      pb[ks][n] = *(const bf16x8*)&prT[(size_t)(wv * 32 + n * 16 + c) * 192 + ks * 32 + g * 8];
  __syncthreads();  // stage16 drained
  bf16x8 vb[2][2];
#pragma unroll
  for (int kk = 0; kk < 2; kk++)
#pragma unroll
    for (int nd = 0; nd < 2; nd++) {
      union { u16 u[8]; bf16x8 v; } bb;
#pragma unroll
      for (int j = 0; j < 8; j++)
        bb.u[j] = lv[(kk * 32 + g * 8 + j) * 192 + h * 32 + nd * 16 + c];
      vb[kk][nd] = bb.v;
    }
  __syncthreads();  // lv dead
  f32x4 acc[4][4] = {};
  __builtin_amdgcn_s_setprio(1);
#pragma unroll
  for (int m = 0; m < 4; m++)
#pragma unroll
    for (int n = 0; n < 4; n++) acc[m][n] = mfma16(kb[m], qa[n], acc[m][n]);
  __builtin_amdgcn_s_setprio(0);
  const u16* rg = rpbg + h * 4096;
  f32x4 oacc[4][2] = {};
#pragma unroll
  for (int n = 0; n < 4; n++) {
    ushort4 rv[4];
#pragma unroll
    for (int m = 0; m < 4; m++)
      rv[m] = *(const ushort4*)&rg[(n * 16 + c) * 64 + m * 16 + g * 4];
    float vals[4][4];
    float mx = -3.4e38f;
#pragma unroll
    for (int m = 0; m < 4; m++) {
      float mr[4] = {mv[n][m].x, mv[n][m].y, mv[n][m].z, mv[n][m].w};
      u16 ru[4] = {rv[m].x, rv[m].y, rv[m].z, rv[m].w};
#pragma unroll
      for (int r = 0; r < 4; r++) {
        vals[m][r] = acc[m][n][r] + bf2f(ru[r]) + mr[r];
        mx = fmaxf(mx, vals[m][r]);
      }
    }
    mx = fmaxf(mx, __shfl_xor(mx, 16, 64));
    mx = fmaxf(mx, __shfl_xor(mx, 32, 64));
    float sum = 0.f;
#pragma unroll
    for (int m = 0; m < 4; m++)
#pragma unroll
      for (int r = 0; r < 4; r++) { vals[m][r] = __expf(vals[m][r] - mx); sum += vals[m][r]; }
    sum += __shfl_xor(sum, 16, 64);
    sum += __shfl_xor(sum, 32, 64);
    float inv = 1.f / sum;
#pragma unroll
    for (int m = 0; m < 4; m++) {
      unsigned p0 = f2bf(vals[m][0] * inv) | ((unsigned)f2bf(vals[m][1] * inv) << 16);
      unsigned p1 = f2bf(vals[m][2] * inv) | ((unsigned)f2bf(vals[m][3] * inv) << 16);
      *(uint2*)&lp[h * 1152 + c * 72 + m * 16 + g * 4] = make_uint2(p0, p1);
    }
    __builtin_amdgcn_s_setprio(1);
#pragma unroll
    for (int kk = 0; kk < 2; kk++) {
      bf16x8 pa = *(const bf16x8*)&lp[h * 1152 + c * 72 + kk * 32 + g * 8];
#pragma unroll
      for (int nd = 0; nd < 2; nd++) oacc[n][nd] = mfma16(pa, vb[kk][nd], oacc[n][nd]);
    }
    __builtin_amdgcn_s_setprio(0);
  }
  __syncthreads();  // all PV done -> lp dead -> lo writable
#pragma unroll
  for (int m = 0; m < 4; m++)
#pragma unroll
    for (int nd = 0; nd < 2; nd++)
#pragma unroll
      for (int r = 0; r < 4; r++)
        lo[(m * 16 + g * 4 + r) * 200 + h * 32 + nd * 16 + c] = f2bf(oacc[m][nd][r]);
  __syncthreads();
  f32x4 pacc[4][2] = {};
  __builtin_amdgcn_s_setprio(1);
#pragma unroll
  for (int ks = 0; ks < 6; ks++) {
    bf16x8 pa[4];
#pragma unroll
    for (int m = 0; m < 4; m++)
      pa[m] = *(const bf16x8*)&lo[(m * 16 + c) * 200 + ks * 32 + g * 8];
#pragma unroll
    for (int n = 0; n < 2; n++)
#pragma unroll
      for (int m = 0; m < 4; m++) pacc[m][n] = mfma16(pa[m], pb[ks][n], pacc[m][n]);
  }
  __builtin_amdgcn_s_setprio(0);
#pragma unroll
  for (int m = 0; m < 4; m++)
#pragma unroll
    for (int r = 0; r < 4; r++) {
      int tok = m * 16 + g * 4 + r;
#pragma unroll
      for (int n = 0; n < 2; n++) {
        int col = wv * 32 + n * 16 + c;
        pox[((size_t)b_ * 64 + tok) * 192 + col] = f2bf(pacc[m][n][r] + proj_b[col]);
      }
    }
}

// ---------------- K4: fused LN2 + MLP (r17 structure; native bf16 converts) ----
__global__ __launch_bounds__(512) void k_mlp(
    const float* __restrict__ x, const u16* __restrict__ pox,
    const float* __restrict__ g2, const float* __restrict__ b2,
    const u16* __restrict__ f1T, const u16* __restrict__ f2T,
    const float* __restrict__ b1, const float* __restrict__ b2f,
    u16* __restrict__ yb, float* __restrict__ out) {
  __shared__ u16 lds[33792];          // f1c 12288 | f2c 12288 | h1c 8x1152
  u16* f1c = lds;
  u16* f2c = lds + 12288;
  u16* h1c = lds + 24576;
  int tid = threadIdx.x, l = tid & 63, wv = tid >> 6, g = l >> 4, c = l & 15;
  size_t tok0 = (size_t)blockIdx.x * 128 + wv * 16;
  u16* tile = h1c + wv * 1152;        // wave-private [16][72]
#pragma unroll
  for (int i = 0; i < 3; i++) {
    int CI = i * 512 + tid;
    int row = CI / 24, chs = CI % 24;
    int sch = (chs & 24) | ((chs ^ row) & 7);
    stage16(f1T + (size_t)row * 192 + sch * 8, f1c + (i * 512 + wv * 64) * 8, l);
  }
#pragma unroll
  for (int i = 0; i < 3; i++) {
    int CI = i * 512 + tid;
    int row = CI >> 3, chs = CI & 7;
    int sch = chs ^ (row & 7);
    stage16(f2T + (size_t)row * 768 + sch * 8, f2c + (i * 512 + wv * 64) * 8, l);
  }
  int t = (int)tok0 + c;
  int bI = t >> 15, llt = t & 32767;
  int s = llt >> 10, hh = (llt >> 5) & 31, w = llt & 31;
  int s_ = (s - SHIFT) & 31, h_ = (hh - SHIFT) & 31, w_ = (w - SHIFT) & 31;
  int wI = ((s_ >> 2) * 8 + (h_ >> 2)) * 8 + (w_ >> 2);
  int nn = ((s_ & 3) * 4 + (h_ & 3)) * 4 + (w_ & 3);
  size_t wrow = ((size_t)(bI * 512 + wI) * 64 + nn) * 192;
  bf16x8 hb[6];
  float ss = 0.f, sq = 0.f;
#pragma unroll
  for (int ks = 0; ks < 6; ks++) {
    int ch0 = ks * 32 + g * 8;
    union { u16x8 p; u16 u[8]; } pk;
    pk.p = *(const u16x8*)&pox[wrow + ch0];
    float4 xa = *(const float4*)&x[(size_t)t * 192 + ch0];
    float4 xb = *(const float4*)&x[(size_t)t * 192 + ch0 + 4];
    float y[8] = {xa.x, xa.y, xa.z, xa.w, xb.x, xb.y, xb.z, xb.w};
    union { u16 u[8]; u16x8 v; bf16x8 bv; } yy;
#pragma unroll
    for (int j = 0; j < 8; j++) {
      y[j] += bf2f(pk.u[j]);
      ss += y[j]; sq += y[j] * y[j];
      yy.u[j] = f2bf(y[j]);
    }
    *(u16x8*)&yb[(size_t)t * 192 + ch0] = yy.v;
    hb[ks] = yy.bv;
  }
  ss += __shfl_xor(ss, 16, 64); ss += __shfl_xor(ss, 32, 64);
  sq += __shfl_xor(sq, 16, 64); sq += __shfl_xor(sq, 32, 64);
  {
    float mu = ss * (1.f / 192.f);
    float rs = rsqrtf(sq * (1.f / 192.f) - mu * mu + 1e-5f);
#pragma unroll
    for (int ks = 0; ks < 6; ks++) {
      int ch0 = ks * 32 + g * 8;
      float4 ga = *(const float4*)&g2[ch0];
      float4 gb = *(const float4*)&g2[ch0 + 4];
      float4 ba = *(const float4*)&b2[ch0];
      float4 bb = *(const float4*)&b2[ch0 + 4];
      float gv[8] = {ga.x, ga.y, ga.z, ga.w, gb.x, gb.y, gb.z, gb.w};
      float bv[8] = {ba.x, ba.y, ba.z, ba.w, bb.x, bb.y, bb.z, bb.w};
      union { u16x8 v; u16 u[8]; bf16x8 bvv; } yy, hn_;
      yy.bvv = hb[ks];
#pragma unroll
      for (int j = 0; j < 8; j++)
        hn_.u[j] = f2bf((bf2f(yy.u[j]) - mu) * rs * gv[j] + bv[j]);
      hb[ks] = hn_.bvv;
    }
  }
  __syncthreads();
  f32x4 acc2[12] = {};
#pragma unroll 1
  for (int ko = 0; ko < 12; ko++) {
    f32x4 acc1[4] = {};
#pragma unroll
    for (int ks = 0; ks < 6; ks++) {
      int ch = ks * 4 + g;
      int chp = (ch & 24) | ((ch ^ c) & 7);
#pragma unroll
      for (int cf = 0; cf < 4; cf++) {
        bf16x8 wa = *(const bf16x8*)&f1c[(cf * 16 + c) * 192 + chp * 8];
        acc1[cf] = mfma16(wa, hb[ks], acc1[cf]);
      }
    }
#pragma unroll
    for (int cf = 0; cf < 4; cf++) {
      float4 b1v = *(const float4*)&b1[ko * 64 + cf * 16 + g * 4];
      unsigned pk[2];
#pragma unroll
      for (int p = 0; p < 2; p++) {
        unsigned lohi[2];
#pragma unroll
        for (int q = 0; q < 2; q++) {
          int r = p * 2 + q;
          float v = acc1[cf][r] + (r == 0 ? b1v.x : r == 1 ? b1v.y : r == 2 ? b1v.z : b1v.w);
          float u2 = v * (1.5957691216f + 0.0713548163f * v * v);
          v = v * (1.f / (1.f + __expf(-u2)));
          lohi[q] = f2bf(v);
        }
        pk[p] = lohi[0] | (lohi[1] << 16);
      }
      *(uint2*)&tile[c * 72 + cf * 16 + g * 4] = make_uint2(pk[0], pk[1]);
    }
    __syncthreads();
    if (ko < 11) {
#pragma unroll
      for (int i = 0; i < 3; i++) {
        int CI = i * 512 + tid;
        int row = CI / 24, chs = CI % 24;
        int sch = (chs & 24) | ((chs ^ row) & 7);
        stage16(f1T + (size_t)((ko + 1) * 64 + row) * 192 + sch * 8,
                f1c + (i * 512 + wv * 64) * 8, l);
      }
    }
#pragma unroll
    for (int ck = 0; ck < 2; ck++) {
      bf16x8 a2 = *(const bf16x8*)&tile[c * 72 + ck * 32 + g * 8];
      int ch = ck * 4 + g;
      int chp = ch ^ (c & 7);
#pragma unroll
      for (int of = 0; of < 12; of++) {
        bf16x8 wb = *(const bf16x8*)&f2c[(of * 16 + c) * 64 + chp * 8];
        acc2[of] = mfma16(a2, wb, acc2[of]);
      }
    }
    __syncthreads();
    if (ko < 11) {
#pragma unroll
      for (int i = 0; i < 3; i++) {
        int CI = i * 512 + tid;
        int row = CI >> 3, chs = CI & 7;
        int sch = chs ^ (row & 7);
        stage16(f2T + (size_t)row * 768 + (ko + 1) * 64 + sch * 8,
                f2c + (i * 512 + wv * 64) * 8, l);
      }
    }
  }
#pragma unroll
  for (int of = 0; of < 12; of++) {
    int col = of * 16 + c;
    float bb = b2f[col];
#pragma unroll
    for (int r = 0; r < 4; r++) {
      size_t trow = tok0 + g * 4 + r;
      size_t base = trow * 192 + col;
      out[base] = acc2[of][r] + bb + bf2f(yb[base]);
    }
  }
}

extern "C" void kernel_launch(void* const* d_in, const int* in_sizes, int n_in,
                              void* d_out, int out_size, void* d_ws, size_t ws_size,
                              hipStream_t stream) {
  const float* x      = (const float*)d_in[0];
  const float* mask   = (const float*)d_in[1];
  const float* skip   = (const float*)d_in[2];
  const float* x_up   = (const float*)d_in[3];
  const float* n1g    = (const float*)d_in[4];
  const float* n1b    = (const float*)d_in[5];
  const float* kv_w   = (const float*)d_in[6];
  const float* kv_b   = (const float*)d_in[7];
  const float* rpb    = (const float*)d_in[8];
  const float* proj_w = (const float*)d_in[9];
  const float* proj_b = (const float*)d_in[10];
  const float* n2g    = (const float*)d_in[11];
  const float* n2b    = (const float*)d_in[12];
  const float* fc1_w  = (const float*)d_in[13];
  const float* fc1_b  = (const float*)d_in[14];
  const float* fc2_w  = (const float*)d_in[15];
  const float* fc2_b  = (const float*)d_in[16];
  char* ws = (char*)d_ws;
  u16* kvT  = (u16*)(ws + OFF_KVWT);
  u16* prT  = (u16*)(ws + OFF_PRWT);
  u16* f1T  = (u16*)(ws + OFF_FC1WT);
  u16* f2T  = (u16*)(ws + OFF_FC2WT);
  u16* skw  = (u16*)(ws + OFF_SKW);
  u16* qw   = (u16*)(ws + OFF_QW);
  u16* kvb  = (u16*)(ws + OFF_KVB);
  u16* pox  = (u16*)(ws + OFF_POX);
  u16* yb   = (u16*)(ws + OFF_YB);
  u16* rpbg = (u16*)(ws + OFF_RPBG);
  float* out = (float*)d_out;

  k_prep<<<dim3(576), dim3(256), 0, stream>>>(kv_w, proj_w, fc1_w, fc2_w, rpb,
                                              kvT, prT, f1T, f2T, rpbg);
  k_ln_part<<<dim3(16384), dim3(256), 0, stream>>>(skip, x_up, n1g, n1b, skw, qw);
  k_kv<<<dim3(512, 2), dim3(256), 0, stream>>>(skw, kvT, kv_b, kvb);
  k_attn_mega<<<dim3(1024), dim3(384), 0, stream>>>(
      qw, kvb, rpbg, mask, prT, proj_b, pox);
  k_mlp<<<dim3(512), dim3(512), 0, stream>>>(
      x, pox, n2g, n2b, f1T, f2T, fc1_b, fc2_b, yb, out);
}